// Round 16
// baseline (316.048 us; speedup 1.0000x reference)
//
#include <hip/hip_runtime.h>
#include <hip/hip_bf16.h>

// Problem constants
#define Bn   4
#define CHn  96
#define Hh   48
#define Ww   48
#define Ll   2304      // H*W
#define Pp   9216      // B*L
#define DIn  192
#define Nn   16
#define Rr   6
#define Sseg   32      // scan segments per sequence
#define SEGL   72      // 2304 / 32
#define NCH     9      // 72 / 8 chunks
#define HSPLIT 884736  // hinit split boundary (floats)

__device__ inline float siluf(float x){ return x / (1.0f + __expf(-x)); }
__device__ inline float sigmf(float x){ return 1.0f / (1.0f + __expf(-x)); }

__device__ inline int pix_of(int k, int l){
  if (k == 0) return l;
  if (k == 1) return (l % 48) * 48 + l / 48;
  if (k == 2) return Ll - 1 - l;
  int lr = Ll - 1 - l; return (lr % 48) * 48 + lr / 48;
}
// row index l for direction k such that pix_of(k,l) == p
__device__ inline int l_of(int k, int p){
  if (k == 0) return p;
  if (k == 1) return (p % 48) * 48 + p / 48;
  if (k == 2) return Ll - 1 - p;
  return Ll - 1 - ((p % 48) * 48 + p / 48);
}

// split-region hinit accessor (boundary is a multiple of 256 -> float4 never straddles)
__device__ inline float4* hptr(float* lo, float* hi, size_t idx){
  return (float4*)(idx < HSPLIT ? lo + idx : hi + (idx - HSPLIT));
}

// ---------------- transpose-all-weights kernel (one launch) ----------------
struct TArgs {
  const float* s[14];
  float* d[14];
  int rows[14];
  int cols[14];
};
__global__ void k_tr(TArgs a){
  int id = blockIdx.y;
  int n = a.rows[id] * a.cols[id];
  int t = blockIdx.x * blockDim.x + threadIdx.x;
  if (t < n){
    int r = t / a.cols[id];
    int c = t - r * a.cols[id];
    a.d[id][c * a.rows[id] + r] = a.s[id][t];
  }
}

// ---- conv1x1 + BN + ReLU + channel linear; 16-pixel tiles, reads NCHW x directly ----
__global__ __launch_bounds__(256) void k_pre(const float* __restrict__ x, const float* __restrict__ w1T, const float* __restrict__ b1,
                      const float* __restrict__ bng, const float* __restrict__ bnb,
                      const float* __restrict__ linT, const float* __restrict__ lb,
                      float* __restrict__ hlin){
  __shared__ float xv[16][97];
  __shared__ float hv[16][97];
  int tid = threadIdx.x;
  int m = tid >> 4, t = tid & 15;
  int p0 = blockIdx.x * 16;
  int b = p0 / Ll; int pp0 = p0 - b * Ll;
  #pragma unroll
  for (int it = 0; it < 6; ++it){
    int e = it * 256 + tid; int c = e >> 4; int mm = e & 15;
    xv[mm][c] = x[((size_t)(b * CHn + c)) * Ll + pp0 + mm];
  }
  __syncthreads();
  float acc[6];
  #pragma unroll
  for (int j = 0; j < 6; ++j) acc[j] = 0.f;
  for (int i = 0; i < CHn; ++i){
    float xval = xv[m][i];
    #pragma unroll
    for (int j = 0; j < 6; ++j)
      acc[j] = fmaf(w1T[i * CHn + t + 16 * j], xval, acc[j]);
  }
  #pragma unroll
  for (int j = 0; j < 6; ++j){
    int c = t + 16 * j;
    float s = bng[c] * rsqrtf(1.0f + 1e-5f);
    hv[m][c] = fmaxf((acc[j] + b1[c]) * s + bnb[c], 0.f);
  }
  __syncthreads();
  float a2[6];
  #pragma unroll
  for (int j = 0; j < 6; ++j) a2[j] = lb[t + 16 * j];
  for (int i = 0; i < CHn; ++i){
    float hval = hv[m][i];
    #pragma unroll
    for (int j = 0; j < 6; ++j)
      a2[j] = fmaf(linT[i * CHn + t + 16 * j], hval, a2[j]);
  }
  int p = p0 + m;
  #pragma unroll
  for (int j = 0; j < 6; ++j)
    hlin[(size_t)p * CHn + t + 16 * j] = a2[j];
}

// ---------------- two depthwise 3x3 convs + SiLU ----------------
__global__ void k_dw(const float* __restrict__ hlin,
                     const float* __restrict__ dw1w, const float* __restrict__ dw1b,
                     const float* __restrict__ dw2w, const float* __restrict__ dw2b,
                     float* __restrict__ x1pre, float* __restrict__ x2){
  int t = blockIdx.x * 256 + threadIdx.x;
  if (t >= Pp * CHn) return;
  int c = t % CHn; int p = t / CHn; int b = p / Ll; int pp = p - b * Ll;
  int r = pp / Ww; int cx = pp - r * Ww;
  float a1 = dw1b[c], a2 = dw2b[c];
  for (int dy = -1; dy <= 1; ++dy){
    int ny = r + dy; if ((unsigned)ny >= Hh) continue;
    for (int dx = -1; dx <= 1; ++dx){
      int nx = cx + dx; if ((unsigned)nx >= Ww) continue;
      float v = hlin[(size_t)((b * Ll) + ny * Ww + nx) * CHn + c];
      int wi = c * 9 + (dy + 1) * 3 + (dx + 1);
      a1 = fmaf(dw1w[wi], v, a1);
      a2 = fmaf(dw2w[wi], v, a2);
    }
  }
  x1pre[t] = siluf(a1);
  x2[t]   = siluf(a2);
}

// ---- attention gate; 16-pixel tiles ----
__global__ __launch_bounds__(256) void k_gate(const float* __restrict__ x2,
                       const float* __restrict__ ag1T, const float* __restrict__ ag1b,
                       const float* __restrict__ ag2T, const float* __restrict__ ag2b,
                       float* __restrict__ x2g){
  __shared__ float xv[16][97];
  __shared__ float rv[16][49];
  int tid = threadIdx.x;
  int m = tid >> 4, t = tid & 15;
  int p0 = blockIdx.x * 16;
  #pragma unroll
  for (int it = 0; it < 6; ++it){
    int e = it * 256 + tid; int mm = e / 96; int c = e - mm * 96;
    xv[mm][c] = x2[(size_t)(p0 + mm) * CHn + c];
  }
  __syncthreads();
  float a[3];
  #pragma unroll
  for (int jj = 0; jj < 3; ++jj) a[jj] = ag1b[t + 16 * jj];
  for (int i = 0; i < CHn; ++i){
    float xval = xv[m][i];
    #pragma unroll
    for (int jj = 0; jj < 3; ++jj)
      a[jj] = fmaf(ag1T[i * 48 + t + 16 * jj], xval, a[jj]);
  }
  #pragma unroll
  for (int jj = 0; jj < 3; ++jj) rv[m][t + 16 * jj] = fmaxf(a[jj], 0.f);
  __syncthreads();
  float a2[6];
  #pragma unroll
  for (int j = 0; j < 6; ++j) a2[j] = ag2b[t + 16 * j];
  for (int i = 0; i < 48; ++i){
    float rval = rv[m][i];
    #pragma unroll
    for (int j = 0; j < 6; ++j)
      a2[j] = fmaf(ag2T[i * CHn + t + 16 * j], rval, a2[j]);
  }
  int p = p0 + m;
  #pragma unroll
  for (int j = 0; j < 6; ++j){
    int c = t + 16 * j;
    x2g[(size_t)p * CHn + c] = xv[m][c] * sigmf(a2[j]);
  }
}

// ---- SS2D input projection v2: vectorized LDS weight reads; 1728 blocks ----
__global__ __launch_bounds__(256) void k_ssin(const float* __restrict__ x1pre, const float* __restrict__ inT,
                                              float* __restrict__ xi, float* __restrict__ z){
  __shared__ float Xs[32][17];
  __shared__ float Wsh[32][128];
  int tid = threadIdx.x;
  int mt = blockIdx.x % 576; int nt = blockIdx.x / 576;
  int p0 = mt * 16, n0 = nt * 128;
  int tx = tid & 15, ty = tid >> 4;
  float accA[4], accB[4];
  #pragma unroll
  for (int j = 0; j < 4; ++j){ accA[j] = 0.f; accB[j] = 0.f; }
  for (int kc = 0; kc < 96; kc += 32){
    #pragma unroll
    for (int it = 0; it < 2; ++it){
      int e = it * 256 + tid; int dd = e & 31; int m = e >> 5;
      Xs[dd][m] = x1pre[(size_t)(p0 + m) * CHn + kc + dd];
    }
    #pragma unroll
    for (int it = 0; it < 16; ++it){
      int e = it * 256 + tid; int n = e & 127; int dd = e >> 7;
      Wsh[dd][n] = inT[(size_t)(kc + dd) * 384 + n0 + n];
    }
    __syncthreads();
    #pragma unroll
    for (int dd = 0; dd < 32; ++dd){
      float xv = Xs[dd][ty];
      float4 wa = *(const float4*)&Wsh[dd][tx * 4];
      float4 wb = *(const float4*)&Wsh[dd][64 + tx * 4];
      accA[0] = fmaf(xv, wa.x, accA[0]); accA[1] = fmaf(xv, wa.y, accA[1]);
      accA[2] = fmaf(xv, wa.z, accA[2]); accA[3] = fmaf(xv, wa.w, accA[3]);
      accB[0] = fmaf(xv, wb.x, accB[0]); accB[1] = fmaf(xv, wb.y, accB[1]);
      accB[2] = fmaf(xv, wb.z, accB[2]); accB[3] = fmaf(xv, wb.w, accB[3]);
    }
    __syncthreads();
  }
  int p = p0 + ty;
  int na = n0 + tx * 4;
  int nb2 = n0 + 64 + tx * 4;
  float4 va = make_float4(accA[0], accA[1], accA[2], accA[3]);
  float4 vb = make_float4(accB[0], accB[1], accB[2], accB[3]);
  if (na < 192) *(float4*)&xi[(size_t)p * DIn + na] = va;
  else          *(float4*)&z [(size_t)p * DIn + (na - 192)] = va;
  if (nb2 < 192) *(float4*)&xi[(size_t)p * DIn + nb2] = vb;
  else           *(float4*)&z [(size_t)p * DIn + (nb2 - 192)] = vb;
}

// ---- SS2D depthwise 3x3 + SiLU; also writes transposed copy xcT ----
__global__ void k_ssdw(const float* __restrict__ xi, const float* __restrict__ scw,
                       const float* __restrict__ scb, float* __restrict__ xc,
                       float* __restrict__ xcT){
  int t = blockIdx.x * 256 + threadIdx.x;
  if (t >= Pp * DIn) return;
  int d = t % DIn; int p = t / DIn; int b = p / Ll; int pp = p - b * Ll;
  int r = pp / Ww; int cx = pp - r * Ww;
  float a = scb[d];
  for (int dy = -1; dy <= 1; ++dy){
    int ny = r + dy; if ((unsigned)ny >= Hh) continue;
    for (int dx = -1; dx <= 1; ++dx){
      int nx = cx + dx; if ((unsigned)nx >= Ww) continue;
      float v = xi[(size_t)((b * Ll) + ny * Ww + nx) * DIn + d];
      a = fmaf(scw[d * 9 + (dy + 1) * 3 + (dx + 1)], v, a);
    }
  }
  float val = siluf(a);
  xc[t] = val;
  int lt = cx * 48 + r;
  xcT[((size_t)(b * Ll) + lt) * DIn + d] = val;
}

// ---- xproj GEMM v3: M-tile 32, split-K 6, vectorized LDS weight reads; 1728 blocks ----
__global__ __launch_bounds__(256) void k_xproj(const float* __restrict__ xc,
    const float* __restrict__ xpwT, float* __restrict__ part){
  __shared__ float Xs[32][33];
  __shared__ float Wsh[32][160];
  int tid = threadIdx.x;
  int mt = blockIdx.x / 6; int kc = (blockIdx.x - mt * 6) * 32;
  int p0g = mt * 32;
  int tx = tid & 15, ty = tid >> 4;
  const float* xbase = xc + (size_t)p0g * DIn + kc;
  #pragma unroll
  for (int it = 0; it < 4; ++it){
    int e = it * 256 + tid; int dd = e & 31; int m = e >> 5;
    Xs[dd][m] = xbase[(size_t)m * DIn + dd];
  }
  #pragma unroll
  for (int it = 0; it < 20; ++it){
    int e = it * 256 + tid; int dd = e / 160; int n = e - dd * 160;
    Wsh[dd][n] = (n < 152) ? xpwT[(size_t)(kc + dd) * 152 + n] : 0.f;
  }
  __syncthreads();
  float a0[4], a1[4], b0[4], b1[4], c0[2], c1[2];
  #pragma unroll
  for (int i = 0; i < 4; ++i){ a0[i] = a1[i] = b0[i] = b1[i] = 0.f; }
  c0[0] = c0[1] = c1[0] = c1[1] = 0.f;
  #pragma unroll
  for (int dd = 0; dd < 32; ++dd){
    float x0 = Xs[dd][ty];
    float x1 = Xs[dd][ty + 16];
    float4 wa = *(const float4*)&Wsh[dd][tx * 4];
    float4 wb = *(const float4*)&Wsh[dd][64 + tx * 4];
    float2 wc = *(const float2*)&Wsh[dd][128 + tx * 2];
    a0[0] = fmaf(x0, wa.x, a0[0]); a0[1] = fmaf(x0, wa.y, a0[1]);
    a0[2] = fmaf(x0, wa.z, a0[2]); a0[3] = fmaf(x0, wa.w, a0[3]);
    a1[0] = fmaf(x1, wa.x, a1[0]); a1[1] = fmaf(x1, wa.y, a1[1]);
    a1[2] = fmaf(x1, wa.z, a1[2]); a1[3] = fmaf(x1, wa.w, a1[3]);
    b0[0] = fmaf(x0, wb.x, b0[0]); b0[1] = fmaf(x0, wb.y, b0[1]);
    b0[2] = fmaf(x0, wb.z, b0[2]); b0[3] = fmaf(x0, wb.w, b0[3]);
    b1[0] = fmaf(x1, wb.x, b1[0]); b1[1] = fmaf(x1, wb.y, b1[1]);
    b1[2] = fmaf(x1, wb.z, b1[2]); b1[3] = fmaf(x1, wb.w, b1[3]);
    c0[0] = fmaf(x0, wc.x, c0[0]); c0[1] = fmaf(x0, wc.y, c0[1]);
    c1[0] = fmaf(x1, wc.x, c1[0]); c1[1] = fmaf(x1, wc.y, c1[1]);
  }
  float* pb0 = part + ((size_t)blockIdx.x * 32 + ty) * 152;
  float* pb1 = part + ((size_t)blockIdx.x * 32 + ty + 16) * 152;
  #pragma unroll
  for (int i = 0; i < 4; ++i){
    pb0[tx * 4 + i] = a0[i];      pb1[tx * 4 + i] = a1[i];
    pb0[64 + tx * 4 + i] = b0[i]; pb1[64 + tx * 4 + i] = b1[i];
  }
  #pragma unroll
  for (int i = 0; i < 2; ++i){
    int n = 128 + tx * 2 + i;
    if (n < 152){ pb0[n] = c0[i]; pb1[n] = c1[i]; }
  }
}

// ---------------- xred: sum 6 partials + scatter B/C + dt-rank (32-pixel tiles) ----------------
__global__ void k_xred(const float* __restrict__ part, float* __restrict__ bc,
                       float* __restrict__ dtsG){
  int t = blockIdx.x * 256 + threadIdx.x;
  if (t >= Pp * 152) return;
  int p = t / 152, n = t - p * 152;
  int mt = p >> 5, m = p & 31;
  const float* pb = part + ((size_t)(mt * 6) * 32 + m) * 152 + n;
  float s = 0.f;
  #pragma unroll
  for (int kc = 0; kc < 6; ++kc) s += pb[(size_t)kc * 32 * 152];
  int b = p / Ll; int pp = p - b * Ll;
  int k = n / 38, jj = n - k * 38;
  int l = l_of(k, pp);
  if (jj < 6) dtsG[((size_t)((b * 4 + k) * Ll + l)) * 6 + jj] = s;
  else        bc [((size_t)((b * 4 + k) * Ll + l)) * 32 + (jj - 6)] = s;
}

// ======================= segmented selective scan (dt recomputed in-scan) =======================

// ---- pass A: local scan per segment (h0=0), emit h_end + sum(dt) ----
__global__ __launch_bounds__(64) void k_scanA(const float* __restrict__ dtsG, const float* __restrict__ dtwT,
                                              const float* __restrict__ dtb,
                                              const float* __restrict__ xc, const float* __restrict__ xcT,
                                              const float* __restrict__ bc, const float* __restrict__ Alog,
                                              float* __restrict__ hend, float* __restrict__ dtsum){
  int blk = blockIdx.x; int unit = blk >> 5; int seg = blk & 31;
  int g = unit % 12; int bk = unit / 12; int k = bk & 3; int b = bk >> 2;
  int lane = threadIdx.x; int ch = lane >> 2; int ns = lane & 3; int nb = ns * 4;
  int d = g * 16 + ch;
  const int arow = (k * DIn + d) * 16 + nb;
  float A0 = -__expf(Alog[arow + 0]);
  float A1 = -__expf(Alog[arow + 1]);
  float A2 = -__expf(Alog[arow + 2]);
  float A3 = -__expf(Alog[arow + 3]);
  float dtw_r[6];
  #pragma unroll
  for (int r = 0; r < 6; ++r) dtw_r[r] = dtwT[r * 768 + k * DIn + d];
  float dtbv = dtb[k * DIn + d];
  float h0 = 0.f, h1 = 0.f, h2 = 0.f, h3 = 0.f, dacc = 0.f;

  const int l0 = seg * SEGL;
  const float* dsbase = dtsG + (size_t)(bk * Ll + l0) * 6;
  const float* ubase = ((k & 1) ? xcT : xc) + (size_t)(b * Ll) * DIn + g * 16;
  bool rev = (k & 2) != 0;
  const float* bbase = bc + ((size_t)(bk * Ll) + l0) * 32;

  __shared__ float dsl[2][48];
  __shared__ float ul[2][128];
  __shared__ float blA[2][128];

  float dsr = (lane < 48) ? dsbase[lane] : 0.f;
  float ur0, ur1;
  {
    int idx = lane; int row = idx >> 4, col = idx & 15;
    int l = l0 + row; int lr = rev ? (Ll - 1 - l) : l;
    ur0 = ubase[(size_t)lr * DIn + col];
    idx = 64 + lane; row = idx >> 4; col = idx & 15;
    l = l0 + row; lr = rev ? (Ll - 1 - l) : l;
    ur1 = ubase[(size_t)lr * DIn + col];
  }
  float4 bn = make_float4(0.f,0.f,0.f,0.f);
  if (lane < 32) bn = *(const float4*)(bbase + (size_t)(lane >> 2) * 32 + (lane & 3) * 4);
  if (lane < 48) dsl[0][lane] = dsr;
  ul[0][lane] = ur0; ul[0][64 + lane] = ur1;
  if (lane < 32) *(float4*)&blA[0][lane * 4] = bn;
  __syncthreads();

  for (int cc = 0; cc < NCH; ++cc){
    bool more = (cc + 1 < NCH);
    if (more){
      dsr = (lane < 48) ? dsbase[(cc + 1) * 48 + lane] : 0.f;
      int idx = lane; int row = idx >> 4, col = idx & 15;
      int l = l0 + (cc + 1) * 8 + row; int lr = rev ? (Ll - 1 - l) : l;
      ur0 = ubase[(size_t)lr * DIn + col];
      idx = 64 + lane; row = idx >> 4; col = idx & 15;
      l = l0 + (cc + 1) * 8 + row; lr = rev ? (Ll - 1 - l) : l;
      ur1 = ubase[(size_t)lr * DIn + col];
      if (lane < 32) bn = *(const float4*)(bbase + (size_t)((cc + 1) * 8 + (lane >> 2)) * 32 + (lane & 3) * 4);
    }
    int buf = cc & 1;
    #pragma unroll
    for (int lp = 0; lp < 8; ++lp){
      const float* dsp = &dsl[buf][lp * 6];
      float a = dtbv;
      #pragma unroll
      for (int r = 0; r < 6; ++r) a = fmaf(dtw_r[r], dsp[r], a);
      float dt = fmaxf(a, 0.f) + __logf(1.0f + __expf(-fabsf(a)));
      float u = ul[buf][lp * 16 + ch];
      float du = dt * u;
      float4 Bv = *(const float4*)&blA[buf][lp * 16 + nb];
      dacc += dt;
      h0 = fmaf(h0, __expf(dt * A0), du * Bv.x);
      h1 = fmaf(h1, __expf(dt * A1), du * Bv.y);
      h2 = fmaf(h2, __expf(dt * A2), du * Bv.z);
      h3 = fmaf(h3, __expf(dt * A3), du * Bv.w);
    }
    __syncthreads();
    if (more){
      int b2 = buf ^ 1;
      if (lane < 48) dsl[b2][lane] = dsr;
      ul[b2][lane] = ur0; ul[b2][64 + lane] = ur1;
      if (lane < 32) *(float4*)&blA[b2][lane * 4] = bn;
    }
    __syncthreads();
  }
  size_t sb = (size_t)unit * Sseg + seg;
  *(float4*)&hend[sb * 256 + lane * 4] = make_float4(h0, h1, h2, h3);
  if (ns == 0) dtsum[sb * 16 + ch] = dacc;
}

// ---- combine: sequential fold over segments -> h_init per segment; also zeroes ysum ----
__global__ __launch_bounds__(64) void k_comb(const float* __restrict__ Alog, const float* __restrict__ hend,
                                             const float* __restrict__ dtsum,
                                             float* __restrict__ hlo, float* __restrict__ hhi,
                                             float* __restrict__ ysum){
  int unit = blockIdx.x; int g = unit % 12; int bk = unit / 12; int k = bk & 3;
  int lane = threadIdx.x; int ch = lane >> 2; int ns = lane & 3; int nb = ns * 4;
  {
    size_t zbase = ((size_t)unit * 64 + lane) * 144;
    float4 z4 = make_float4(0.f, 0.f, 0.f, 0.f);
    #pragma unroll
    for (int i = 0; i < 36; ++i)
      *(float4*)&ysum[zbase + i * 4] = z4;
  }
  int d = g * 16 + ch;
  const int arow = (k * DIn + d) * 16 + nb;
  float A0 = -__expf(Alog[arow + 0]);
  float A1 = -__expf(Alog[arow + 1]);
  float A2 = -__expf(Alog[arow + 2]);
  float A3 = -__expf(Alog[arow + 3]);
  float h0 = 0.f, h1 = 0.f, h2 = 0.f, h3 = 0.f;
  for (int s = 0; s < Sseg; ++s){
    size_t sb = (size_t)unit * Sseg + s;
    *hptr(hlo, hhi, sb * 256 + lane * 4) = make_float4(h0, h1, h2, h3);
    float dsv = dtsum[sb * 16 + ch];
    float4 he = *(const float4*)&hend[sb * 256 + lane * 4];
    h0 = fmaf(h0, __expf(A0 * dsv), he.x);
    h1 = fmaf(h1, __expf(A1 * dsv), he.y);
    h2 = fmaf(h2, __expf(A2 * dsv), he.z);
    h3 = fmaf(h3, __expf(A3 * dsv), he.w);
  }
}

// ---- pass B: rescan from h_init, atomically accumulate y into ysum[b][pix][d] ----
__global__ __launch_bounds__(64) void k_scanB(const float* __restrict__ dtsG, const float* __restrict__ dtwT,
                                              const float* __restrict__ dtb,
                                              const float* __restrict__ xc, const float* __restrict__ xcT,
                                              const float* __restrict__ bc, const float* __restrict__ Alog,
                                              float* __restrict__ hlo, float* __restrict__ hhi,
                                              float* __restrict__ ysum){
  int blk = blockIdx.x; int unit = blk >> 5; int seg = blk & 31;
  int g = unit % 12; int bk = unit / 12; int k = bk & 3; int b = bk >> 2;
  int lane = threadIdx.x; int ch = lane >> 2; int ns = lane & 3; int nb = ns * 4;
  int d = g * 16 + ch;
  const int arow = (k * DIn + d) * 16 + nb;
  float A0 = -__expf(Alog[arow + 0]);
  float A1 = -__expf(Alog[arow + 1]);
  float A2 = -__expf(Alog[arow + 2]);
  float A3 = -__expf(Alog[arow + 3]);
  float dtw_r[6];
  #pragma unroll
  for (int r = 0; r < 6; ++r) dtw_r[r] = dtwT[r * 768 + k * DIn + d];
  float dtbv = dtb[k * DIn + d];
  size_t sb = (size_t)unit * Sseg + seg;
  float4 hi = *hptr(hlo, hhi, sb * 256 + lane * 4);
  float h0 = hi.x, h1 = hi.y, h2 = hi.z, h3 = hi.w;

  const int l0 = seg * SEGL;
  const float* dsbase = dtsG + (size_t)(bk * Ll + l0) * 6;
  const float* ubase = ((k & 1) ? xcT : xc) + (size_t)(b * Ll) * DIn + g * 16;
  bool rev = (k & 2) != 0;
  const float* bbase = bc + ((size_t)(bk * Ll) + l0) * 32;
  float* ybase = ysum + (size_t)(b * Ll) * DIn + d;

  __shared__ float dsl[2][48];
  __shared__ float ul[2][128];
  __shared__ float bl[2][256];

  float dsr = (lane < 48) ? dsbase[lane] : 0.f;
  float ur0, ur1;
  {
    int idx = lane; int row = idx >> 4, col = idx & 15;
    int l = l0 + row; int lr = rev ? (Ll - 1 - l) : l;
    ur0 = ubase[(size_t)lr * DIn + col];
    idx = 64 + lane; row = idx >> 4; col = idx & 15;
    l = l0 + row; lr = rev ? (Ll - 1 - l) : l;
    ur1 = ubase[(size_t)lr * DIn + col];
  }
  float4 bn = *(const float4*)(bbase + lane * 4);
  if (lane < 48) dsl[0][lane] = dsr;
  ul[0][lane] = ur0; ul[0][64 + lane] = ur1;
  *(float4*)&bl[0][lane * 4] = bn;
  __syncthreads();

  for (int cc = 0; cc < NCH; ++cc){
    bool more = (cc + 1 < NCH);
    if (more){
      dsr = (lane < 48) ? dsbase[(cc + 1) * 48 + lane] : 0.f;
      int idx = lane; int row = idx >> 4, col = idx & 15;
      int l = l0 + (cc + 1) * 8 + row; int lr = rev ? (Ll - 1 - l) : l;
      ur0 = ubase[(size_t)lr * DIn + col];
      idx = 64 + lane; row = idx >> 4; col = idx & 15;
      l = l0 + (cc + 1) * 8 + row; lr = rev ? (Ll - 1 - l) : l;
      ur1 = ubase[(size_t)lr * DIn + col];
      bn = *(const float4*)(bbase + (size_t)(cc + 1) * 256 + lane * 4);
    }
    int buf = cc & 1;
    #pragma unroll
    for (int lp = 0; lp < 8; ++lp){
      const float* dsp = &dsl[buf][lp * 6];
      float a = dtbv;
      #pragma unroll
      for (int r = 0; r < 6; ++r) a = fmaf(dtw_r[r], dsp[r], a);
      float dt = fmaxf(a, 0.f) + __logf(1.0f + __expf(-fabsf(a)));
      float u = ul[buf][lp * 16 + ch];
      float du = dt * u;
      float4 Bv = *(const float4*)&bl[buf][lp * 32 + nb];
      float4 Cv = *(const float4*)&bl[buf][lp * 32 + 16 + nb];
      h0 = fmaf(h0, __expf(dt * A0), du * Bv.x);
      h1 = fmaf(h1, __expf(dt * A1), du * Bv.y);
      h2 = fmaf(h2, __expf(dt * A2), du * Bv.z);
      h3 = fmaf(h3, __expf(dt * A3), du * Bv.w);
      float yp = fmaf(h0, Cv.x, fmaf(h1, Cv.y, fmaf(h2, Cv.z, h3 * Cv.w)));
      yp += __shfl_xor(yp, 1);
      yp += __shfl_xor(yp, 2);
      if (ns == 0){
        int l = l0 + cc * 8 + lp;
        int pix = pix_of(k, l);
        atomicAdd(ybase + (size_t)pix * DIn, yp);
      }
    }
    __syncthreads();
    if (more){
      int b2 = buf ^ 1;
      if (lane < 48) dsl[b2][lane] = dsr;
      ul[b2][lane] = ur0; ul[b2][64 + lane] = ur1;
      *(float4*)&bl[b2][lane * 4] = bn;
    }
    __syncthreads();
  }
}

// ---- lngate: D*u + LN(192) + silu(z) gate; 1 wave = 1 pixel, 2304 blocks ----
__global__ __launch_bounds__(256) void k_lngate(const float* __restrict__ ysum, const float* __restrict__ xc,
                        const float* __restrict__ z, const float* __restrict__ Dp,
                        const float* __restrict__ ong, const float* __restrict__ onb,
                        float* __restrict__ ygb){
  int tid = threadIdx.x;
  int w = tid >> 6;       // pixel within block (wave index)
  int l = tid & 63;
  int p = blockIdx.x * 4 + w;
  const float* yrow = ysum + (size_t)p * DIn;
  const float* urow = xc   + (size_t)p * DIn;
  const float* zrow = z    + (size_t)p * DIn;
  float yv[3]; float s1 = 0.f;
  #pragma unroll
  for (int j = 0; j < 3; ++j){
    int d = l + 64 * j;
    float Ds = Dp[d] + Dp[192 + d] + Dp[384 + d] + Dp[576 + d];
    float v = fmaf(urow[d], Ds, yrow[d]);
    yv[j] = v; s1 += v;
  }
  #pragma unroll
  for (int mk = 1; mk < 64; mk <<= 1) s1 += __shfl_xor(s1, mk, 64);
  float mu = s1 * (1.f / 192.f);
  float s2 = 0.f;
  #pragma unroll
  for (int j = 0; j < 3; ++j){ float dv = yv[j] - mu; s2 += dv * dv; }
  #pragma unroll
  for (int mk = 1; mk < 64; mk <<= 1) s2 += __shfl_xor(s2, mk, 64);
  float rstd = rsqrtf(s2 * (1.f / 192.f) + 1e-5f);
  #pragma unroll
  for (int j = 0; j < 3; ++j){
    int d = l + 64 * j;
    float yn = (yv[j] - mu) * rstd * ong[d] + onb[d];
    float zv = zrow[d];
    ygb[(size_t)p * DIn + d] = yn * (zv * sigmf(zv));
  }
}

// ---- oproj v2: GEMM 9216x96 over K=192, split-K=2, vectorized LDS reads; 1152 blocks ----
__global__ __launch_bounds__(256) void k_oproj(const float* __restrict__ ygb, const float* __restrict__ owT,
                       float* __restrict__ part2){
  __shared__ float Xs[32][17];
  __shared__ float Wsh[32][100];
  int tid = threadIdx.x;
  int mt = blockIdx.x >> 1; int kh = (blockIdx.x & 1) * 96;
  int p0 = mt * 16;
  int tx = tid & 15, ty = tid >> 4;
  float aA[4], aB[2];
  aA[0] = aA[1] = aA[2] = aA[3] = 0.f; aB[0] = aB[1] = 0.f;
  for (int kc = 0; kc < 96; kc += 32){
    #pragma unroll
    for (int it = 0; it < 2; ++it){
      int e = it * 256 + tid; int dd = e & 31; int m = e >> 5;
      Xs[dd][m] = ygb[(size_t)(p0 + m) * DIn + kh + kc + dd];
    }
    #pragma unroll
    for (int it = 0; it < 12; ++it){
      int e = it * 256 + tid; int dd = e / 96; int n = e - dd * 96;
      Wsh[dd][n] = owT[(size_t)(kh + kc + dd) * 96 + n];
    }
    __syncthreads();
    #pragma unroll
    for (int dd = 0; dd < 32; ++dd){
      float xv = Xs[dd][ty];
      float4 wa = *(const float4*)&Wsh[dd][tx * 4];
      float2 wb = *(const float2*)&Wsh[dd][64 + tx * 2];
      aA[0] = fmaf(xv, wa.x, aA[0]); aA[1] = fmaf(xv, wa.y, aA[1]);
      aA[2] = fmaf(xv, wa.z, aA[2]); aA[3] = fmaf(xv, wa.w, aA[3]);
      aB[0] = fmaf(xv, wb.x, aB[0]); aB[1] = fmaf(xv, wb.y, aB[1]);
    }
    __syncthreads();
  }
  float* pb = part2 + ((size_t)blockIdx.x * 16 + ty) * 96;
  #pragma unroll
  for (int i = 0; i < 4; ++i) pb[tx * 4 + i] = aA[i];
  #pragma unroll
  for (int i = 0; i < 2; ++i) pb[64 + tx * 2 + i] = aB[i];
}

// ---- finc: sum 2 partials + x2g + LN(96) + squeeze convs -> ul; also zeroes csum ----
__global__ __launch_bounds__(256) void k_finc(const float* __restrict__ part2, const float* __restrict__ x2g,
                      const float* __restrict__ lng, const float* __restrict__ lnb,
                      const float* __restrict__ sq1T, const float* __restrict__ sq2T,
                      float* __restrict__ ul, float* __restrict__ csum){
  __shared__ float crs_s[16 * 104];
  __shared__ float sqs[2304];
  int tid = threadIdx.x;
  int m = tid >> 4, t = tid & 15;
  int mt = blockIdx.x;
  int p = mt * 16 + m;
  if (mt < 4 && tid < 192) csum[mt * 192 + tid] = 0.f;
  #pragma unroll
  for (int it = 0; it < 5; ++it){
    int e = it * 256 + tid;
    if (e < 1152) sqs[e] = sq1T[e];
  }
  #pragma unroll
  for (int it = 0; it < 5; ++it){
    int e = it * 256 + tid;
    if (e < 1152) sqs[1152 + e] = sq2T[e];
  }
  const float* pa = part2 + ((size_t)(mt * 2)     * 16 + m) * 96;
  const float* pbp = part2 + ((size_t)(mt * 2 + 1) * 16 + m) * 96;
  float sv[6]; float s3 = 0.f;
  #pragma unroll
  for (int jj = 0; jj < 6; ++jj){
    int c = t + 16 * jj;
    float v = pa[c] + pbp[c] + x2g[(size_t)p * CHn + c];
    sv[jj] = v; s3 += v;
  }
  #pragma unroll
  for (int mk = 1; mk < 16; mk <<= 1) s3 += __shfl_xor(s3, mk, 16);
  float mu2 = s3 * (1.f / 96.f);
  float s4 = 0.f;
  #pragma unroll
  for (int jj = 0; jj < 6; ++jj){ float dv = sv[jj] - mu2; s4 += dv * dv; }
  #pragma unroll
  for (int mk = 1; mk < 16; mk <<= 1) s4 += __shfl_xor(s4, mk, 16);
  float rstd2 = rsqrtf(s4 * (1.f / 96.f) + 1e-5f);
  #pragma unroll
  for (int jj = 0; jj < 6; ++jj){
    int c = t + 16 * jj;
    crs_s[m * 104 + c] = (sv[jj] - mu2) * rstd2 * lng[c] + lnb[c];
  }
  __syncthreads();
  const float* cr = &crs_s[m * 104];
  #pragma unroll
  for (int jj = 0; jj < 3; ++jj){
    int o = t + 16 * jj;
    float a = 0.f;
    if (o < 24){
      for (int i = 0; i < 48; ++i) a = fmaf(sqs[i * 24 + o], cr[i], a);
    } else {
      int oo = o - 24;
      for (int i = 0; i < 48; ++i) a = fmaf(sqs[1152 + i * 24 + oo], cr[48 + i], a);
    }
    ul[(size_t)p * 48 + o] = a;
  }
}

// ---- CRM main v5; 16-pixel row tiles; halo in LDS; fused channel-mean reduction ----
__global__ __launch_bounds__(256) void k_y(const float* __restrict__ ul, const float* __restrict__ gwcT,
                    const float* __restrict__ gwcb, const float* __restrict__ pwc1T,
                    const float* __restrict__ pwc2T, float* __restrict__ Ybig,
                    float* __restrict__ csum){
  __shared__ float uls[3 * 18 * 48];   // 10.4 KB
  __shared__ float sA[192];
  int tid = threadIdx.x;
  int m = tid >> 4, t = tid & 15;
  int blk = blockIdx.x;
  int b = blk / 144; int rem = blk - b * 144;
  int r = rem / 3; int chunk = rem - r * 3;
  int cx0 = chunk * 16;
  for (int e = tid; e < 3 * 18 * 48; e += 256){
    int ch = e % 48; int rc = e / 48;
    int col = rc % 18; int row = rc / 18;
    int gr = r - 1 + row; int gc = cx0 - 1 + col;
    float v = 0.f;
    if ((unsigned)gr < Hh && (unsigned)gc < Ww)
      v = ul[((size_t)(b * Ll + gr * Ww + gc)) * 48 + ch];
    uls[e] = v;
  }
  if (tid < 192) sA[tid] = 0.f;
  __syncthreads();
  int p = b * Ll + r * Ww + cx0 + m;
  const float* u1 = &uls[(1 * 18 + m + 1) * 48];
  float* yout = Ybig + (size_t)p * 192;
  #pragma unroll 1
  for (int j = 0; j < 6; ++j){
    int oc = t + 16 * j;
    int grp = oc / 48;
    float acc = gwcb[oc];
    #pragma unroll 1
    for (int k9 = 0; k9 < 9; ++k9){
      int dy = k9 / 3; int dx = k9 - dy * 3;
      const float* un = &uls[((dy * 18) + m + dx) * 48 + grp * 12];
      const float* wrow = gwcT + k9 * 96 + oc;
      #pragma unroll
      for (int i = 0; i < 12; ++i)
        acc = fmaf(wrow[i * 864], un[i], acc);   // gwcT[(i*9+k9)*96+oc]
    }
    #pragma unroll
    for (int i = 0; i < 24; ++i) acc = fmaf(pwc1T[i * 96 + oc], u1[i], acc);
    yout[oc] = acc;
    float s = acc + __shfl_xor(acc, 16);
    s += __shfl_xor(s, 32);
    if ((tid & 48) == 0) atomicAdd(&sA[oc], s);
  }
  #pragma unroll 1
  for (int j = 6; j < 12; ++j){
    int oc = t + 16 * j;
    float acc;
    if (oc < 168){
      int o2 = oc - 96; acc = 0.f;
      #pragma unroll
      for (int i = 0; i < 24; ++i) acc = fmaf(pwc2T[i * 72 + o2], u1[24 + i], acc);
    } else {
      acc = u1[24 + oc - 168];
    }
    yout[oc] = acc;
    float s = acc + __shfl_xor(acc, 16);
    s += __shfl_xor(s, 32);
    if ((tid & 48) == 0) atomicAdd(&sA[oc], s);
  }
  __syncthreads();
  if (tid < 192) atomicAdd(&csum[b * 192 + tid], sA[tid]);
}

// ---------------- softmax over 192 channel means ----------------
__global__ void k_softmax(const float* __restrict__ csum, float* __restrict__ wsm){
  int b = blockIdx.x; int t = threadIdx.x;
  __shared__ float red[192];
  float m = csum[b * 192 + t] * (1.f / 2304.f);
  red[t] = m; __syncthreads();
  if (t < 96) red[t] = fmaxf(red[t], red[t + 96]); __syncthreads();
  if (t < 48) red[t] = fmaxf(red[t], red[t + 48]); __syncthreads();
  if (t < 24) red[t] = fmaxf(red[t], red[t + 24]); __syncthreads();
  if (t < 12) red[t] = fmaxf(red[t], red[t + 12]); __syncthreads();
  if (t < 6)  red[t] = fmaxf(red[t], red[t + 6]);  __syncthreads();
  float mx = fmaxf(fmaxf(fmaxf(red[0], red[1]), fmaxf(red[2], red[3])), fmaxf(red[4], red[5]));
  __syncthreads();
  float e = __expf(m - mx);
  red[t] = e; __syncthreads();
  if (t < 96) red[t] += red[t + 96]; __syncthreads();
  if (t < 48) red[t] += red[t + 48]; __syncthreads();
  if (t < 24) red[t] += red[t + 24]; __syncthreads();
  if (t < 12) red[t] += red[t + 12]; __syncthreads();
  if (t < 6)  red[t] += red[t + 6];  __syncthreads();
  float s = red[0] + red[1] + red[2] + red[3] + red[4] + red[5];
  wsm[b * 192 + t] = e / s;
}

// ---- weighted halves + final linear; 16-pixel tiles, writes NCHW out directly ----
__global__ __launch_bounds__(256) void k_final(const float* __restrict__ Ybig, const float* __restrict__ wsm,
                        const float* __restrict__ finT, const float* __restrict__ finb,
                        float* __restrict__ out){
  __shared__ float ys[16][193];
  __shared__ float ov[16][97];
  __shared__ float wv[192];
  int tid = threadIdx.x;
  int m = tid >> 4, t = tid & 15;
  int p0 = blockIdx.x * 16;
  int b = p0 / Ll; int pp0 = p0 - b * Ll;
  if (tid < 192) wv[tid] = wsm[b * 192 + tid];
  #pragma unroll
  for (int it = 0; it < 12; ++it){
    int e = it * 256 + tid; int mm = e / 192; int c = e - mm * 192;
    ys[mm][c] = Ybig[(size_t)(p0 + mm) * 192 + c];
  }
  __syncthreads();
  #pragma unroll
  for (int j = 0; j < 6; ++j){
    int c = t + 16 * j;
    ov[m][c] = wv[c] * ys[m][c] + wv[96 + c] * ys[m][96 + c];
  }
  __syncthreads();
  float res[6];
  #pragma unroll
  for (int j = 0; j < 6; ++j) res[j] = finb[t + 16 * j];
  for (int i = 0; i < 96; ++i){
    float oval = ov[m][i];
    #pragma unroll
    for (int j = 0; j < 6; ++j)
      res[j] = fmaf(finT[i * 96 + t + 16 * j], oval, res[j]);
  }
  #pragma unroll
  for (int j = 0; j < 6; ++j) ys[m][t + 16 * j] = res[j];
  __syncthreads();
  #pragma unroll
  for (int it = 0; it < 6; ++it){
    int e = it * 256 + tid; int c = e >> 4; int mm = e & 15;
    out[((size_t)(b * CHn + c)) * Ll + pp0 + mm] = ys[mm][c];
  }
}

// ---------------- host launch ----------------
extern "C" void kernel_launch(void* const* d_in, const int* in_sizes, int n_in,
                              void* d_out, int out_size, void* d_ws, size_t ws_size,
                              hipStream_t stream) {
  const float* x     = (const float*)d_in[0];
  const float* w1    = (const float*)d_in[1];
  const float* b1    = (const float*)d_in[2];
  const float* bng   = (const float*)d_in[3];
  const float* bnb   = (const float*)d_in[4];
  const float* linw  = (const float*)d_in[5];
  const float* linb  = (const float*)d_in[6];
  const float* dw1w  = (const float*)d_in[7];
  const float* dw1b  = (const float*)d_in[8];
  const float* dw2w  = (const float*)d_in[9];
  const float* dw2b  = (const float*)d_in[10];
  const float* ag1w  = (const float*)d_in[11];
  const float* ag1b  = (const float*)d_in[12];
  const float* ag2w  = (const float*)d_in[13];
  const float* ag2b  = (const float*)d_in[14];
  const float* lng   = (const float*)d_in[15];
  const float* lnb   = (const float*)d_in[16];
  const float* sq1w  = (const float*)d_in[17];
  const float* sq2w  = (const float*)d_in[18];
  const float* gwcw  = (const float*)d_in[19];
  const float* gwcb  = (const float*)d_in[20];
  const float* pwc1w = (const float*)d_in[21];
  const float* pwc2w = (const float*)d_in[22];
  const float* finw  = (const float*)d_in[23];
  const float* finb  = (const float*)d_in[24];
  const float* inw   = (const float*)d_in[25];
  const float* scw   = (const float*)d_in[26];
  const float* scb   = (const float*)d_in[27];
  const float* xpw   = (const float*)d_in[28];
  const float* dtw   = (const float*)d_in[29];
  const float* dtb   = (const float*)d_in[30];
  const float* Alog  = (const float*)d_in[31];
  const float* Dp    = (const float*)d_in[32];
  const float* ong   = (const float*)d_in[33];
  const float* onb   = (const float*)d_in[34];
  const float* oww   = (const float*)d_in[35];

  float* ws = (float*)d_ws;
  float* hlin   = ws + 0;         // 884736
  float* dtsum  = ws + 442368;    // 98304  (scanA->comb)
  float* x1pre  = ws + 884736;    // 884736: x1pre; hinit_lo; csum later
  float* x2     = ws + 1769472;   // 884736: x2; hinit_hi
  float* x2g    = ws + 2654208;   // 884736
  float* xibuf  = ws + 3538944;   // 1769472: xi; hend; Ybig
  float* zbuf   = ws + 5308416;   // 1769472
  float* xcbuf  = ws + 7077888;   // 1769472
  float* packed = ws + 8847360;   // 14155776: part + dtsG; ygb/part2 after scans
  float* bcbuf  = ws + 23003136;  // 1179648
  float* ysum   = ws + 24182784;  // 1769472
  float* wT     = ws + 25952256;  // 142656 weights
  float* xcTbuf = ws + 26094912;  // 1769472

  float* hend    = xibuf;
  float* hinitlo = x1pre;
  float* hinithi = x2;
  float* ulb     = hlin;
  float* Ybig    = xibuf;
  float* csum_p  = x1pre;
  float* wsmb    = x1pre + 1024;
  float* part    = packed;                 // 8404992 floats (k_xproj->k_xred)
  float* dtsG    = packed + 8404992;       // 221184  (k_xred->scans)
  float* ygb     = packed;                 // after scans
  float* part2   = packed + 1769472;

  float* w1T   = wT + 0;
  float* linT  = wT + 9216;
  float* ag1T  = wT + 18432;
  float* ag2T  = wT + 23040;
  float* inT   = wT + 27648;
  float* owT   = wT + 64512;
  float* pwc1T = wT + 82944;
  float* pwc2T = wT + 85248;
  float* finT  = wT + 86976;
  float* sq1T  = wT + 96192;
  float* sq2T  = wT + 97344;
  float* gwcT  = wT + 98496;
  float* dtwT  = wT + 108864;
  float* xpwT  = wT + 113472;

  TArgs ta;
  const float* srcs[14] = {w1, linw, ag1w, ag2w, inw, oww, pwc1w, pwc2w, finw, sq1w, sq2w, gwcw, dtw, xpw};
  float* dsts[14]       = {w1T, linT, ag1T, ag2T, inT, owT, pwc1T, pwc2T, finT, sq1T, sq2T, gwcT, dtwT, xpwT};
  int rows[14] = {96, 96, 48, 96, 384, 96, 96, 72, 96, 24, 24, 96, 768, 152};
  int cols[14] = {96, 96, 96, 48, 96, 192, 24, 24, 96, 48, 48, 108, 6, 192};
  for (int i = 0; i < 14; ++i){ ta.s[i] = srcs[i]; ta.d[i] = dsts[i]; ta.rows[i] = rows[i]; ta.cols[i] = cols[i]; }

  k_tr<<<dim3(144, 14), 256, 0, stream>>>(ta);
  k_pre<<<576, 256, 0, stream>>>(x, w1T, b1, bng, bnb, linT, linb, hlin);
  k_dw<<<(Pp * CHn) / 256, 256, 0, stream>>>(hlin, dw1w, dw1b, dw2w, dw2b, x1pre, x2);
  k_gate<<<576, 256, 0, stream>>>(x2, ag1T, ag1b, ag2T, ag2b, x2g);
  k_ssin<<<576 * 3, 256, 0, stream>>>(x1pre, inT, xibuf, zbuf);
  k_ssdw<<<(Pp * DIn) / 256, 256, 0, stream>>>(xibuf, scw, scb, xcbuf, xcTbuf);
  k_xproj<<<288 * 6, 256, 0, stream>>>(xcbuf, xpwT, part);
  k_xred<<<(Pp * 152 + 255) / 256, 256, 0, stream>>>(part, bcbuf, dtsG);
  k_scanA<<<192 * Sseg, 64, 0, stream>>>(dtsG, dtwT, dtb, xcbuf, xcTbuf, bcbuf, Alog, hend, dtsum);
  k_comb<<<192, 64, 0, stream>>>(Alog, hend, dtsum, hinitlo, hinithi, ysum);
  k_scanB<<<192 * Sseg, 64, 0, stream>>>(dtsG, dtwT, dtb, xcbuf, xcTbuf, bcbuf, Alog, hinitlo, hinithi, ysum);
  k_lngate<<<2304, 256, 0, stream>>>(ysum, xcbuf, zbuf, Dp, ong, onb, ygb);
  k_oproj<<<1152, 256, 0, stream>>>(ygb, owT, part2);
  k_finc<<<576, 256, 0, stream>>>(part2, x2g, lng, lnb, sq1T, sq2T, ulb, csum_p);
  k_y<<<576, 256, 0, stream>>>(ulb, gwcT, gwcb, pwc1T, pwc2T, Ybig, csum_p);
  k_softmax<<<4, 192, 0, stream>>>(csum_p, wsmb);
  k_final<<<576, 256, 0, stream>>>(Ybig, wsmb, finT, finb, (float*)d_out);
}

// Round 18
// 303.602 us; speedup vs baseline: 1.0410x; 1.0410x over previous
//
#include <hip/hip_runtime.h>
#include <hip/hip_bf16.h>

// Problem constants
#define Bn   4
#define CHn  96
#define Hh   48
#define Ww   48
#define Ll   2304      // H*W
#define Pp   9216      // B*L
#define DIn  192
#define Nn   16
#define Rr   6
#define Sseg   32      // scan segments per sequence
#define SEGL   72      // 2304 / 32
#define NCH     9      // 72 / 8 chunks
#define HSPLIT 884736  // hinit split boundary (floats)

__device__ inline float siluf(float x){ return x / (1.0f + __expf(-x)); }
__device__ inline float sigmf(float x){ return 1.0f / (1.0f + __expf(-x)); }

__device__ inline int pix_of(int k, int l){
  if (k == 0) return l;
  if (k == 1) return (l % 48) * 48 + l / 48;
  if (k == 2) return Ll - 1 - l;
  int lr = Ll - 1 - l; return (lr % 48) * 48 + lr / 48;
}
// row index l for direction k such that pix_of(k,l) == p
__device__ inline int l_of(int k, int p){
  if (k == 0) return p;
  if (k == 1) return (p % 48) * 48 + p / 48;
  if (k == 2) return Ll - 1 - p;
  return Ll - 1 - ((p % 48) * 48 + p / 48);
}

// split-region hinit accessor (boundary is a multiple of 256 -> float4 never straddles)
__device__ inline float4* hptr(float* lo, float* hi, size_t idx){
  return (float4*)(idx < HSPLIT ? lo + idx : hi + (idx - HSPLIT));
}

// 4x bf16 (as uint2) -> float4, exact shift conversion
__device__ inline float4 bf4(uint2 r){
  return make_float4(
    __uint_as_float((r.x & 0xffffu) << 16),
    __uint_as_float(r.x & 0xffff0000u),
    __uint_as_float((r.y & 0xffffu) << 16),
    __uint_as_float(r.y & 0xffff0000u));
}

// ---------------- transpose-all-weights kernel (one launch) ----------------
struct TArgs {
  const float* s[14];
  float* d[14];
  int rows[14];
  int cols[14];
};
__global__ void k_tr(TArgs a){
  int id = blockIdx.y;
  int n = a.rows[id] * a.cols[id];
  int t = blockIdx.x * blockDim.x + threadIdx.x;
  if (t < n){
    int r = t / a.cols[id];
    int c = t - r * a.cols[id];
    a.d[id][c * a.rows[id] + r] = a.s[id][t];
  }
}

// ---- conv1x1 + BN + ReLU + channel linear; 16-pixel tiles, reads NCHW x directly ----
__global__ __launch_bounds__(256) void k_pre(const float* __restrict__ x, const float* __restrict__ w1T, const float* __restrict__ b1,
                      const float* __restrict__ bng, const float* __restrict__ bnb,
                      const float* __restrict__ linT, const float* __restrict__ lb,
                      float* __restrict__ hlin){
  __shared__ float xv[16][97];
  __shared__ float hv[16][97];
  int tid = threadIdx.x;
  int m = tid >> 4, t = tid & 15;
  int p0 = blockIdx.x * 16;
  int b = p0 / Ll; int pp0 = p0 - b * Ll;
  #pragma unroll
  for (int it = 0; it < 6; ++it){
    int e = it * 256 + tid; int c = e >> 4; int mm = e & 15;
    xv[mm][c] = x[((size_t)(b * CHn + c)) * Ll + pp0 + mm];
  }
  __syncthreads();
  float acc[6];
  #pragma unroll
  for (int j = 0; j < 6; ++j) acc[j] = 0.f;
  for (int i = 0; i < CHn; ++i){
    float xval = xv[m][i];
    #pragma unroll
    for (int j = 0; j < 6; ++j)
      acc[j] = fmaf(w1T[i * CHn + t + 16 * j], xval, acc[j]);
  }
  #pragma unroll
  for (int j = 0; j < 6; ++j){
    int c = t + 16 * j;
    float s = bng[c] * rsqrtf(1.0f + 1e-5f);
    hv[m][c] = fmaxf((acc[j] + b1[c]) * s + bnb[c], 0.f);
  }
  __syncthreads();
  float a2[6];
  #pragma unroll
  for (int j = 0; j < 6; ++j) a2[j] = lb[t + 16 * j];
  for (int i = 0; i < CHn; ++i){
    float hval = hv[m][i];
    #pragma unroll
    for (int j = 0; j < 6; ++j)
      a2[j] = fmaf(linT[i * CHn + t + 16 * j], hval, a2[j]);
  }
  int p = p0 + m;
  #pragma unroll
  for (int j = 0; j < 6; ++j)
    hlin[(size_t)p * CHn + t + 16 * j] = a2[j];
}

// ---------------- two depthwise 3x3 convs + SiLU ----------------
__global__ void k_dw(const float* __restrict__ hlin,
                     const float* __restrict__ dw1w, const float* __restrict__ dw1b,
                     const float* __restrict__ dw2w, const float* __restrict__ dw2b,
                     float* __restrict__ x1pre, float* __restrict__ x2){
  int t = blockIdx.x * 256 + threadIdx.x;
  if (t >= Pp * CHn) return;
  int c = t % CHn; int p = t / CHn; int b = p / Ll; int pp = p - b * Ll;
  int r = pp / Ww; int cx = pp - r * Ww;
  float a1 = dw1b[c], a2 = dw2b[c];
  for (int dy = -1; dy <= 1; ++dy){
    int ny = r + dy; if ((unsigned)ny >= Hh) continue;
    for (int dx = -1; dx <= 1; ++dx){
      int nx = cx + dx; if ((unsigned)nx >= Ww) continue;
      float v = hlin[(size_t)((b * Ll) + ny * Ww + nx) * CHn + c];
      int wi = c * 9 + (dy + 1) * 3 + (dx + 1);
      a1 = fmaf(dw1w[wi], v, a1);
      a2 = fmaf(dw2w[wi], v, a2);
    }
  }
  x1pre[t] = siluf(a1);
  x2[t]   = siluf(a2);
}

// ---- attention gate; 16-pixel tiles ----
__global__ __launch_bounds__(256) void k_gate(const float* __restrict__ x2,
                       const float* __restrict__ ag1T, const float* __restrict__ ag1b,
                       const float* __restrict__ ag2T, const float* __restrict__ ag2b,
                       float* __restrict__ x2g){
  __shared__ float xv[16][97];
  __shared__ float rv[16][49];
  int tid = threadIdx.x;
  int m = tid >> 4, t = tid & 15;
  int p0 = blockIdx.x * 16;
  #pragma unroll
  for (int it = 0; it < 6; ++it){
    int e = it * 256 + tid; int mm = e / 96; int c = e - mm * 96;
    xv[mm][c] = x2[(size_t)(p0 + mm) * CHn + c];
  }
  __syncthreads();
  float a[3];
  #pragma unroll
  for (int jj = 0; jj < 3; ++jj) a[jj] = ag1b[t + 16 * jj];
  for (int i = 0; i < CHn; ++i){
    float xval = xv[m][i];
    #pragma unroll
    for (int jj = 0; jj < 3; ++jj)
      a[jj] = fmaf(ag1T[i * 48 + t + 16 * jj], xval, a[jj]);
  }
  #pragma unroll
  for (int jj = 0; jj < 3; ++jj) rv[m][t + 16 * jj] = fmaxf(a[jj], 0.f);
  __syncthreads();
  float a2[6];
  #pragma unroll
  for (int j = 0; j < 6; ++j) a2[j] = ag2b[t + 16 * j];
  for (int i = 0; i < 48; ++i){
    float rval = rv[m][i];
    #pragma unroll
    for (int j = 0; j < 6; ++j)
      a2[j] = fmaf(ag2T[i * CHn + t + 16 * j], rval, a2[j]);
  }
  int p = p0 + m;
  #pragma unroll
  for (int j = 0; j < 6; ++j){
    int c = t + 16 * j;
    x2g[(size_t)p * CHn + c] = xv[m][c] * sigmf(a2[j]);
  }
}

// ---- SS2D input projection v2: vectorized LDS weight reads; 1728 blocks ----
__global__ __launch_bounds__(256) void k_ssin(const float* __restrict__ x1pre, const float* __restrict__ inT,
                                              float* __restrict__ xi, float* __restrict__ z){
  __shared__ float Xs[32][17];
  __shared__ float Wsh[32][128];
  int tid = threadIdx.x;
  int mt = blockIdx.x % 576; int nt = blockIdx.x / 576;
  int p0 = mt * 16, n0 = nt * 128;
  int tx = tid & 15, ty = tid >> 4;
  float accA[4], accB[4];
  #pragma unroll
  for (int j = 0; j < 4; ++j){ accA[j] = 0.f; accB[j] = 0.f; }
  for (int kc = 0; kc < 96; kc += 32){
    #pragma unroll
    for (int it = 0; it < 2; ++it){
      int e = it * 256 + tid; int dd = e & 31; int m = e >> 5;
      Xs[dd][m] = x1pre[(size_t)(p0 + m) * CHn + kc + dd];
    }
    #pragma unroll
    for (int it = 0; it < 16; ++it){
      int e = it * 256 + tid; int n = e & 127; int dd = e >> 7;
      Wsh[dd][n] = inT[(size_t)(kc + dd) * 384 + n0 + n];
    }
    __syncthreads();
    #pragma unroll
    for (int dd = 0; dd < 32; ++dd){
      float xv = Xs[dd][ty];
      float4 wa = *(const float4*)&Wsh[dd][tx * 4];
      float4 wb = *(const float4*)&Wsh[dd][64 + tx * 4];
      accA[0] = fmaf(xv, wa.x, accA[0]); accA[1] = fmaf(xv, wa.y, accA[1]);
      accA[2] = fmaf(xv, wa.z, accA[2]); accA[3] = fmaf(xv, wa.w, accA[3]);
      accB[0] = fmaf(xv, wb.x, accB[0]); accB[1] = fmaf(xv, wb.y, accB[1]);
      accB[2] = fmaf(xv, wb.z, accB[2]); accB[3] = fmaf(xv, wb.w, accB[3]);
    }
    __syncthreads();
  }
  int p = p0 + ty;
  int na = n0 + tx * 4;
  int nb2 = n0 + 64 + tx * 4;
  float4 va = make_float4(accA[0], accA[1], accA[2], accA[3]);
  float4 vb = make_float4(accB[0], accB[1], accB[2], accB[3]);
  if (na < 192) *(float4*)&xi[(size_t)p * DIn + na] = va;
  else          *(float4*)&z [(size_t)p * DIn + (na - 192)] = va;
  if (nb2 < 192) *(float4*)&xi[(size_t)p * DIn + nb2] = vb;
  else           *(float4*)&z [(size_t)p * DIn + (nb2 - 192)] = vb;
}

// ---- SS2D depthwise 3x3 + SiLU; also writes transposed copy xcT ----
__global__ void k_ssdw(const float* __restrict__ xi, const float* __restrict__ scw,
                       const float* __restrict__ scb, float* __restrict__ xc,
                       float* __restrict__ xcT){
  int t = blockIdx.x * 256 + threadIdx.x;
  if (t >= Pp * DIn) return;
  int d = t % DIn; int p = t / DIn; int b = p / Ll; int pp = p - b * Ll;
  int r = pp / Ww; int cx = pp - r * Ww;
  float a = scb[d];
  for (int dy = -1; dy <= 1; ++dy){
    int ny = r + dy; if ((unsigned)ny >= Hh) continue;
    for (int dx = -1; dx <= 1; ++dx){
      int nx = cx + dx; if ((unsigned)nx >= Ww) continue;
      float v = xi[(size_t)((b * Ll) + ny * Ww + nx) * DIn + d];
      a = fmaf(scw[d * 9 + (dy + 1) * 3 + (dx + 1)], v, a);
    }
  }
  float val = siluf(a);
  xc[t] = val;
  int lt = cx * 48 + r;
  xcT[((size_t)(b * Ll) + lt) * DIn + d] = val;
}

// ---- xproj GEMM v3: M-tile 32, split-K 6, vectorized LDS weight reads; 1728 blocks ----
__global__ __launch_bounds__(256) void k_xproj(const float* __restrict__ xc,
    const float* __restrict__ xpwT, float* __restrict__ part){
  __shared__ float Xs[32][33];
  __shared__ float Wsh[32][160];
  int tid = threadIdx.x;
  int mt = blockIdx.x / 6; int kc = (blockIdx.x - mt * 6) * 32;
  int p0g = mt * 32;
  int tx = tid & 15, ty = tid >> 4;
  const float* xbase = xc + (size_t)p0g * DIn + kc;
  #pragma unroll
  for (int it = 0; it < 4; ++it){
    int e = it * 256 + tid; int dd = e & 31; int m = e >> 5;
    Xs[dd][m] = xbase[(size_t)m * DIn + dd];
  }
  #pragma unroll
  for (int it = 0; it < 20; ++it){
    int e = it * 256 + tid; int dd = e / 160; int n = e - dd * 160;
    Wsh[dd][n] = (n < 152) ? xpwT[(size_t)(kc + dd) * 152 + n] : 0.f;
  }
  __syncthreads();
  float a0[4], a1[4], b0[4], b1[4], c0[2], c1[2];
  #pragma unroll
  for (int i = 0; i < 4; ++i){ a0[i] = a1[i] = b0[i] = b1[i] = 0.f; }
  c0[0] = c0[1] = c1[0] = c1[1] = 0.f;
  #pragma unroll
  for (int dd = 0; dd < 32; ++dd){
    float x0 = Xs[dd][ty];
    float x1 = Xs[dd][ty + 16];
    float4 wa = *(const float4*)&Wsh[dd][tx * 4];
    float4 wb = *(const float4*)&Wsh[dd][64 + tx * 4];
    float2 wc = *(const float2*)&Wsh[dd][128 + tx * 2];
    a0[0] = fmaf(x0, wa.x, a0[0]); a0[1] = fmaf(x0, wa.y, a0[1]);
    a0[2] = fmaf(x0, wa.z, a0[2]); a0[3] = fmaf(x0, wa.w, a0[3]);
    a1[0] = fmaf(x1, wa.x, a1[0]); a1[1] = fmaf(x1, wa.y, a1[1]);
    a1[2] = fmaf(x1, wa.z, a1[2]); a1[3] = fmaf(x1, wa.w, a1[3]);
    b0[0] = fmaf(x0, wb.x, b0[0]); b0[1] = fmaf(x0, wb.y, b0[1]);
    b0[2] = fmaf(x0, wb.z, b0[2]); b0[3] = fmaf(x0, wb.w, b0[3]);
    b1[0] = fmaf(x1, wb.x, b1[0]); b1[1] = fmaf(x1, wb.y, b1[1]);
    b1[2] = fmaf(x1, wb.z, b1[2]); b1[3] = fmaf(x1, wb.w, b1[3]);
    c0[0] = fmaf(x0, wc.x, c0[0]); c0[1] = fmaf(x0, wc.y, c0[1]);
    c1[0] = fmaf(x1, wc.x, c1[0]); c1[1] = fmaf(x1, wc.y, c1[1]);
  }
  float* pb0 = part + ((size_t)blockIdx.x * 32 + ty) * 152;
  float* pb1 = part + ((size_t)blockIdx.x * 32 + ty + 16) * 152;
  #pragma unroll
  for (int i = 0; i < 4; ++i){
    pb0[tx * 4 + i] = a0[i];      pb1[tx * 4 + i] = a1[i];
    pb0[64 + tx * 4 + i] = b0[i]; pb1[64 + tx * 4 + i] = b1[i];
  }
  #pragma unroll
  for (int i = 0; i < 2; ++i){
    int n = 128 + tx * 2 + i;
    if (n < 152){ pb0[n] = c0[i]; pb1[n] = c1[i]; }
  }
}

// ---------------- xred: sum 6 partials + scatter B/C + dt-rank (32-pixel tiles) ----------------
__global__ void k_xred(const float* __restrict__ part, float* __restrict__ bc,
                       float* __restrict__ dtsG){
  int t = blockIdx.x * 256 + threadIdx.x;
  if (t >= Pp * 152) return;
  int p = t / 152, n = t - p * 152;
  int mt = p >> 5, m = p & 31;
  const float* pb = part + ((size_t)(mt * 6) * 32 + m) * 152 + n;
  float s = 0.f;
  #pragma unroll
  for (int kc = 0; kc < 6; ++kc) s += pb[(size_t)kc * 32 * 152];
  int b = p / Ll; int pp = p - b * Ll;
  int k = n / 38, jj = n - k * 38;
  int l = l_of(k, pp);
  if (jj < 6) dtsG[((size_t)((b * 4 + k) * Ll + l)) * 6 + jj] = s;
  else        bc [((size_t)((b * 4 + k) * Ll + l)) * 32 + (jj - 6)] = s;
}

// ---- pack v3: delta softplus + contiguous u reads -> bf16 packed[unit][l][dt16|du16] ----
__global__ void k_pack(const float* __restrict__ dtsG, const float* __restrict__ dtwT,
                       const float* __restrict__ dtb, const float* __restrict__ xc,
                       const float* __restrict__ xcT, __hip_bfloat16* __restrict__ packed){
  int t = blockIdx.x * 256 + threadIdx.x;
  if (t >= 36864 * DIn) return;
  int d = t % DIn; int row = t / DIn;
  int bk = row / Ll; int l = row - bk * Ll;
  int k = bk & 3; int b = bk >> 2;
  const float* ds = dtsG + (size_t)row * 6;
  float a = dtb[k * DIn + d];
  #pragma unroll
  for (int r = 0; r < 6; ++r)
    a = fmaf(dtwT[r * 768 + k * DIn + d], ds[r], a);
  float dt = fmaxf(a, 0.f) + __logf(1.0f + __expf(-fabsf(a)));
  int lr = (k & 2) ? (Ll - 1 - l) : l;
  const float* src = (k & 1) ? xcT : xc;
  float u = src[((size_t)(b * Ll) + lr) * DIn + d];
  int unit = bk * 12 + (d >> 4);
  size_t base = ((size_t)unit * Ll + l) * 32 + (d & 15);
  packed[base]      = __float2bfloat16(dt);
  packed[base + 16] = __float2bfloat16(dt * u);
}

// ======================= segmented selective scan =======================

// ---- pass A: local scan per segment (h0=0), emit h_end + sum(dt) ----
__global__ __launch_bounds__(64) void k_scanA(const __hip_bfloat16* __restrict__ packedb, const float* __restrict__ bc,
                                              const float* __restrict__ Alog,
                                              float* __restrict__ hend, float* __restrict__ dtsum){
  int blk = blockIdx.x; int unit = blk >> 5; int seg = blk & 31;
  int g = unit % 12; int bk = unit / 12; int k = bk & 3;
  int lane = threadIdx.x; int ch = lane >> 2; int ns = lane & 3; int nb = ns * 4;
  int d = g * 16 + ch;
  const int arow = (k * DIn + d) * 16 + nb;
  float A0 = -__expf(Alog[arow + 0]);
  float A1 = -__expf(Alog[arow + 1]);
  float A2 = -__expf(Alog[arow + 2]);
  float A3 = -__expf(Alog[arow + 3]);
  float h0 = 0.f, h1 = 0.f, h2 = 0.f, h3 = 0.f, dacc = 0.f;

  const int l0 = seg * SEGL;
  const ushort* pbase = (const ushort*)packedb + ((size_t)unit * Ll + l0) * 32;
  const float* bbase = bc + ((size_t)(bk * Ll) + l0) * 32;

  __shared__ float pl[256];
  __shared__ float blA[128];

  uint2 praw = *(const uint2*)(pbase + lane * 4);
  float4 bn;
  if (lane < 32) bn = *(const float4*)(bbase + (size_t)(lane >> 2) * 32 + (lane & 3) * 4);
  *(float4*)&pl[lane * 4] = bf4(praw);
  if (lane < 32) *(float4*)&blA[lane * 4] = bn;
  __syncthreads();

  for (int cc = 0; cc < NCH; ++cc){
    bool more = (cc + 1 < NCH);
    if (more){
      praw = *(const uint2*)(pbase + (size_t)(cc + 1) * 256 + lane * 4);
      if (lane < 32) bn = *(const float4*)(bbase + (size_t)((cc + 1) * 8 + (lane >> 2)) * 32 + (lane & 3) * 4);
    }
    #pragma unroll
    for (int lp = 0; lp < 8; ++lp){
      float dt = pl[lp * 32 + ch];
      float du = pl[lp * 32 + 16 + ch];
      float4 Bv = *(const float4*)&blA[lp * 16 + nb];
      dacc += dt;
      h0 = fmaf(h0, __expf(dt * A0), du * Bv.x);
      h1 = fmaf(h1, __expf(dt * A1), du * Bv.y);
      h2 = fmaf(h2, __expf(dt * A2), du * Bv.z);
      h3 = fmaf(h3, __expf(dt * A3), du * Bv.w);
    }
    __syncthreads();
    if (more){
      *(float4*)&pl[lane * 4] = bf4(praw);
      if (lane < 32) *(float4*)&blA[lane * 4] = bn;
    }
    __syncthreads();
  }
  size_t sb = (size_t)unit * Sseg + seg;
  *(float4*)&hend[sb * 256 + lane * 4] = make_float4(h0, h1, h2, h3);
  if (ns == 0) dtsum[sb * 16 + ch] = dacc;
}

// ---- combine: sequential fold over segments -> h_init per segment; also zeroes ysum ----
__global__ __launch_bounds__(64) void k_comb(const float* __restrict__ Alog, const float* __restrict__ hend,
                                             const float* __restrict__ dtsum,
                                             float* __restrict__ hlo, float* __restrict__ hhi,
                                             float* __restrict__ ysum){
  int unit = blockIdx.x; int g = unit % 12; int bk = unit / 12; int k = bk & 3;
  int lane = threadIdx.x; int ch = lane >> 2; int ns = lane & 3; int nb = ns * 4;
  {
    size_t zbase = ((size_t)unit * 64 + lane) * 144;
    float4 z4 = make_float4(0.f, 0.f, 0.f, 0.f);
    #pragma unroll
    for (int i = 0; i < 36; ++i)
      *(float4*)&ysum[zbase + i * 4] = z4;
  }
  int d = g * 16 + ch;
  const int arow = (k * DIn + d) * 16 + nb;
  float A0 = -__expf(Alog[arow + 0]);
  float A1 = -__expf(Alog[arow + 1]);
  float A2 = -__expf(Alog[arow + 2]);
  float A3 = -__expf(Alog[arow + 3]);
  float h0 = 0.f, h1 = 0.f, h2 = 0.f, h3 = 0.f;
  for (int s = 0; s < Sseg; ++s){
    size_t sb = (size_t)unit * Sseg + s;
    *hptr(hlo, hhi, sb * 256 + lane * 4) = make_float4(h0, h1, h2, h3);
    float dsv = dtsum[sb * 16 + ch];
    float4 he = *(const float4*)&hend[sb * 256 + lane * 4];
    h0 = fmaf(h0, __expf(A0 * dsv), he.x);
    h1 = fmaf(h1, __expf(A1 * dsv), he.y);
    h2 = fmaf(h2, __expf(A2 * dsv), he.z);
    h3 = fmaf(h3, __expf(A3 * dsv), he.w);
  }
}

// ---- pass B: rescan from h_init, atomically accumulate y into ysum[b][pix][d] ----
__global__ __launch_bounds__(64) void k_scanB(const __hip_bfloat16* __restrict__ packedb, const float* __restrict__ bc,
                                              const float* __restrict__ Alog,
                                              float* __restrict__ hlo, float* __restrict__ hhi,
                                              float* __restrict__ ysum){
  int blk = blockIdx.x; int unit = blk >> 5; int seg = blk & 31;
  int g = unit % 12; int bk = unit / 12; int k = bk & 3; int b = bk >> 2;
  int lane = threadIdx.x; int ch = lane >> 2; int ns = lane & 3; int nb = ns * 4;
  int d = g * 16 + ch;
  const int arow = (k * DIn + d) * 16 + nb;
  float A0 = -__expf(Alog[arow + 0]);
  float A1 = -__expf(Alog[arow + 1]);
  float A2 = -__expf(Alog[arow + 2]);
  float A3 = -__expf(Alog[arow + 3]);
  size_t sb = (size_t)unit * Sseg + seg;
  float4 hi = *hptr(hlo, hhi, sb * 256 + lane * 4);
  float h0 = hi.x, h1 = hi.y, h2 = hi.z, h3 = hi.w;

  const int l0 = seg * SEGL;
  const ushort* pbase = (const ushort*)packedb + ((size_t)unit * Ll + l0) * 32;
  const float* bbase = bc + ((size_t)(bk * Ll) + l0) * 32;
  float* ybase = ysum + (size_t)(b * Ll) * DIn + d;

  __shared__ float pl[256];
  __shared__ float bl[256];

  uint2 praw = *(const uint2*)(pbase + lane * 4);
  float4 bn = *(const float4*)(bbase + lane * 4);
  *(float4*)&pl[lane * 4] = bf4(praw);
  *(float4*)&bl[lane * 4] = bn;
  __syncthreads();

  for (int cc = 0; cc < NCH; ++cc){
    bool more = (cc + 1 < NCH);
    if (more){
      praw = *(const uint2*)(pbase + (size_t)(cc + 1) * 256 + lane * 4);
      bn = *(const float4*)(bbase + (size_t)(cc + 1) * 256 + lane * 4);
    }
    #pragma unroll
    for (int lp = 0; lp < 8; ++lp){
      float dt = pl[lp * 32 + ch];
      float du = pl[lp * 32 + 16 + ch];
      float4 Bv = *(const float4*)&bl[lp * 32 + nb];
      float4 Cv = *(const float4*)&bl[lp * 32 + 16 + nb];
      h0 = fmaf(h0, __expf(dt * A0), du * Bv.x);
      h1 = fmaf(h1, __expf(dt * A1), du * Bv.y);
      h2 = fmaf(h2, __expf(dt * A2), du * Bv.z);
      h3 = fmaf(h3, __expf(dt * A3), du * Bv.w);
      float yp = fmaf(h0, Cv.x, fmaf(h1, Cv.y, fmaf(h2, Cv.z, h3 * Cv.w)));
      yp += __shfl_xor(yp, 1);
      yp += __shfl_xor(yp, 2);
      if (ns == 0){
        int l = l0 + cc * 8 + lp;
        int pix = pix_of(k, l);
        atomicAdd(ybase + (size_t)pix * DIn, yp);
      }
    }
    __syncthreads();
    if (more){
      *(float4*)&pl[lane * 4] = bf4(praw);
      *(float4*)&bl[lane * 4] = bn;
    }
    __syncthreads();
  }
}

// ---- lngate: D*u + LN(192) + silu(z) gate; 1 wave = 1 pixel, 2304 blocks ----
__global__ __launch_bounds__(256) void k_lngate(const float* __restrict__ ysum, const float* __restrict__ xc,
                        const float* __restrict__ z, const float* __restrict__ Dp,
                        const float* __restrict__ ong, const float* __restrict__ onb,
                        float* __restrict__ ygb){
  int tid = threadIdx.x;
  int w = tid >> 6;       // pixel within block (wave index)
  int l = tid & 63;
  int p = blockIdx.x * 4 + w;
  const float* yrow = ysum + (size_t)p * DIn;
  const float* urow = xc   + (size_t)p * DIn;
  const float* zrow = z    + (size_t)p * DIn;
  float yv[3]; float s1 = 0.f;
  #pragma unroll
  for (int j = 0; j < 3; ++j){
    int d = l + 64 * j;
    float Ds = Dp[d] + Dp[192 + d] + Dp[384 + d] + Dp[576 + d];
    float v = fmaf(urow[d], Ds, yrow[d]);
    yv[j] = v; s1 += v;
  }
  #pragma unroll
  for (int mk = 1; mk < 64; mk <<= 1) s1 += __shfl_xor(s1, mk, 64);
  float mu = s1 * (1.f / 192.f);
  float s2 = 0.f;
  #pragma unroll
  for (int j = 0; j < 3; ++j){ float dv = yv[j] - mu; s2 += dv * dv; }
  #pragma unroll
  for (int mk = 1; mk < 64; mk <<= 1) s2 += __shfl_xor(s2, mk, 64);
  float rstd = rsqrtf(s2 * (1.f / 192.f) + 1e-5f);
  #pragma unroll
  for (int j = 0; j < 3; ++j){
    int d = l + 64 * j;
    float yn = (yv[j] - mu) * rstd * ong[d] + onb[d];
    float zv = zrow[d];
    ygb[(size_t)p * DIn + d] = yn * (zv * sigmf(zv));
  }
}

// ---- oproj v2: GEMM 9216x96 over K=192, split-K=2, vectorized LDS reads; 1152 blocks ----
__global__ __launch_bounds__(256) void k_oproj(const float* __restrict__ ygb, const float* __restrict__ owT,
                       float* __restrict__ part2){
  __shared__ float Xs[32][17];
  __shared__ float Wsh[32][100];
  int tid = threadIdx.x;
  int mt = blockIdx.x >> 1; int kh = (blockIdx.x & 1) * 96;
  int p0 = mt * 16;
  int tx = tid & 15, ty = tid >> 4;
  float aA[4], aB[2];
  aA[0] = aA[1] = aA[2] = aA[3] = 0.f; aB[0] = aB[1] = 0.f;
  for (int kc = 0; kc < 96; kc += 32){
    #pragma unroll
    for (int it = 0; it < 2; ++it){
      int e = it * 256 + tid; int dd = e & 31; int m = e >> 5;
      Xs[dd][m] = ygb[(size_t)(p0 + m) * DIn + kh + kc + dd];
    }
    #pragma unroll
    for (int it = 0; it < 12; ++it){
      int e = it * 256 + tid; int dd = e / 96; int n = e - dd * 96;
      Wsh[dd][n] = owT[(size_t)(kh + kc + dd) * 96 + n];
    }
    __syncthreads();
    #pragma unroll
    for (int dd = 0; dd < 32; ++dd){
      float xv = Xs[dd][ty];
      float4 wa = *(const float4*)&Wsh[dd][tx * 4];
      float2 wb = *(const float2*)&Wsh[dd][64 + tx * 2];
      aA[0] = fmaf(xv, wa.x, aA[0]); aA[1] = fmaf(xv, wa.y, aA[1]);
      aA[2] = fmaf(xv, wa.z, aA[2]); aA[3] = fmaf(xv, wa.w, aA[3]);
      aB[0] = fmaf(xv, wb.x, aB[0]); aB[1] = fmaf(xv, wb.y, aB[1]);
    }
    __syncthreads();
  }
  float* pb = part2 + ((size_t)blockIdx.x * 16 + ty) * 96;
  #pragma unroll
  for (int i = 0; i < 4; ++i) pb[tx * 4 + i] = aA[i];
  #pragma unroll
  for (int i = 0; i < 2; ++i) pb[64 + tx * 2 + i] = aB[i];
}

// ---- finc: sum 2 partials + x2g + LN(96) + squeeze convs -> ul; also zeroes csum ----
__global__ __launch_bounds__(256) void k_finc(const float* __restrict__ part2, const float* __restrict__ x2g,
                      const float* __restrict__ lng, const float* __restrict__ lnb,
                      const float* __restrict__ sq1T, const float* __restrict__ sq2T,
                      float* __restrict__ ul, float* __restrict__ csum){
  __shared__ float crs_s[16 * 104];
  __shared__ float sqs[2304];
  int tid = threadIdx.x;
  int m = tid >> 4, t = tid & 15;
  int mt = blockIdx.x;
  int p = mt * 16 + m;
  if (mt < 4 && tid < 192) csum[mt * 192 + tid] = 0.f;
  #pragma unroll
  for (int it = 0; it < 5; ++it){
    int e = it * 256 + tid;
    if (e < 1152) sqs[e] = sq1T[e];
  }
  #pragma unroll
  for (int it = 0; it < 5; ++it){
    int e = it * 256 + tid;
    if (e < 1152) sqs[1152 + e] = sq2T[e];
  }
  const float* pa = part2 + ((size_t)(mt * 2)     * 16 + m) * 96;
  const float* pbp = part2 + ((size_t)(mt * 2 + 1) * 16 + m) * 96;
  float sv[6]; float s3 = 0.f;
  #pragma unroll
  for (int jj = 0; jj < 6; ++jj){
    int c = t + 16 * jj;
    float v = pa[c] + pbp[c] + x2g[(size_t)p * CHn + c];
    sv[jj] = v; s3 += v;
  }
  #pragma unroll
  for (int mk = 1; mk < 16; mk <<= 1) s3 += __shfl_xor(s3, mk, 16);
  float mu2 = s3 * (1.f / 96.f);
  float s4 = 0.f;
  #pragma unroll
  for (int jj = 0; jj < 6; ++jj){ float dv = sv[jj] - mu2; s4 += dv * dv; }
  #pragma unroll
  for (int mk = 1; mk < 16; mk <<= 1) s4 += __shfl_xor(s4, mk, 16);
  float rstd2 = rsqrtf(s4 * (1.f / 96.f) + 1e-5f);
  #pragma unroll
  for (int jj = 0; jj < 6; ++jj){
    int c = t + 16 * jj;
    crs_s[m * 104 + c] = (sv[jj] - mu2) * rstd2 * lng[c] + lnb[c];
  }
  __syncthreads();
  const float* cr = &crs_s[m * 104];
  #pragma unroll
  for (int jj = 0; jj < 3; ++jj){
    int o = t + 16 * jj;
    float a = 0.f;
    if (o < 24){
      for (int i = 0; i < 48; ++i) a = fmaf(sqs[i * 24 + o], cr[i], a);
    } else {
      int oo = o - 24;
      for (int i = 0; i < 48; ++i) a = fmaf(sqs[1152 + i * 24 + oo], cr[48 + i], a);
    }
    ul[(size_t)p * 48 + o] = a;
  }
}

// ---- CRM main v5; 16-pixel row tiles; halo in LDS; fused channel-mean reduction ----
__global__ __launch_bounds__(256) void k_y(const float* __restrict__ ul, const float* __restrict__ gwcT,
                    const float* __restrict__ gwcb, const float* __restrict__ pwc1T,
                    const float* __restrict__ pwc2T, float* __restrict__ Ybig,
                    float* __restrict__ csum){
  __shared__ float uls[3 * 18 * 48];   // 10.4 KB
  __shared__ float sA[192];
  int tid = threadIdx.x;
  int m = tid >> 4, t = tid & 15;
  int blk = blockIdx.x;
  int b = blk / 144; int rem = blk - b * 144;
  int r = rem / 3; int chunk = rem - r * 3;
  int cx0 = chunk * 16;
  for (int e = tid; e < 3 * 18 * 48; e += 256){
    int ch = e % 48; int rc = e / 48;
    int col = rc % 18; int row = rc / 18;
    int gr = r - 1 + row; int gc = cx0 - 1 + col;
    float v = 0.f;
    if ((unsigned)gr < Hh && (unsigned)gc < Ww)
      v = ul[((size_t)(b * Ll + gr * Ww + gc)) * 48 + ch];
    uls[e] = v;
  }
  if (tid < 192) sA[tid] = 0.f;
  __syncthreads();
  int p = b * Ll + r * Ww + cx0 + m;
  const float* u1 = &uls[(1 * 18 + m + 1) * 48];
  float* yout = Ybig + (size_t)p * 192;
  #pragma unroll 1
  for (int j = 0; j < 6; ++j){
    int oc = t + 16 * j;
    int grp = oc / 48;
    float acc = gwcb[oc];
    #pragma unroll 1
    for (int k9 = 0; k9 < 9; ++k9){
      int dy = k9 / 3; int dx = k9 - dy * 3;
      const float* un = &uls[((dy * 18) + m + dx) * 48 + grp * 12];
      const float* wrow = gwcT + k9 * 96 + oc;
      #pragma unroll
      for (int i = 0; i < 12; ++i)
        acc = fmaf(wrow[i * 864], un[i], acc);   // gwcT[(i*9+k9)*96+oc]
    }
    #pragma unroll
    for (int i = 0; i < 24; ++i) acc = fmaf(pwc1T[i * 96 + oc], u1[i], acc);
    yout[oc] = acc;
    float s = acc + __shfl_xor(acc, 16);
    s += __shfl_xor(s, 32);
    if ((tid & 48) == 0) atomicAdd(&sA[oc], s);
  }
  #pragma unroll 1
  for (int j = 6; j < 12; ++j){
    int oc = t + 16 * j;
    float acc;
    if (oc < 168){
      int o2 = oc - 96; acc = 0.f;
      #pragma unroll
      for (int i = 0; i < 24; ++i) acc = fmaf(pwc2T[i * 72 + o2], u1[24 + i], acc);
    } else {
      acc = u1[24 + oc - 168];
    }
    yout[oc] = acc;
    float s = acc + __shfl_xor(acc, 16);
    s += __shfl_xor(s, 32);
    if ((tid & 48) == 0) atomicAdd(&sA[oc], s);
  }
  __syncthreads();
  if (tid < 192) atomicAdd(&csum[b * 192 + tid], sA[tid]);
}

// ---------------- softmax over 192 channel means ----------------
__global__ void k_softmax(const float* __restrict__ csum, float* __restrict__ wsm){
  int b = blockIdx.x; int t = threadIdx.x;
  __shared__ float red[192];
  float m = csum[b * 192 + t] * (1.f / 2304.f);
  red[t] = m; __syncthreads();
  if (t < 96) red[t] = fmaxf(red[t], red[t + 96]); __syncthreads();
  if (t < 48) red[t] = fmaxf(red[t], red[t + 48]); __syncthreads();
  if (t < 24) red[t] = fmaxf(red[t], red[t + 24]); __syncthreads();
  if (t < 12) red[t] = fmaxf(red[t], red[t + 12]); __syncthreads();
  if (t < 6)  red[t] = fmaxf(red[t], red[t + 6]);  __syncthreads();
  float mx = fmaxf(fmaxf(fmaxf(red[0], red[1]), fmaxf(red[2], red[3])), fmaxf(red[4], red[5]));
  __syncthreads();
  float e = __expf(m - mx);
  red[t] = e; __syncthreads();
  if (t < 96) red[t] += red[t + 96]; __syncthreads();
  if (t < 48) red[t] += red[t + 48]; __syncthreads();
  if (t < 24) red[t] += red[t + 24]; __syncthreads();
  if (t < 12) red[t] += red[t + 12]; __syncthreads();
  if (t < 6)  red[t] += red[t + 6];  __syncthreads();
  float s = red[0] + red[1] + red[2] + red[3] + red[4] + red[5];
  wsm[b * 192 + t] = e / s;
}

// ---- weighted halves + final linear; 16-pixel tiles, writes NCHW out directly ----
__global__ __launch_bounds__(256) void k_final(const float* __restrict__ Ybig, const float* __restrict__ wsm,
                        const float* __restrict__ finT, const float* __restrict__ finb,
                        float* __restrict__ out){
  __shared__ float ys[16][193];
  __shared__ float ov[16][97];
  __shared__ float wv[192];
  int tid = threadIdx.x;
  int m = tid >> 4, t = tid & 15;
  int p0 = blockIdx.x * 16;
  int b = p0 / Ll; int pp0 = p0 - b * Ll;
  if (tid < 192) wv[tid] = wsm[b * 192 + tid];
  #pragma unroll
  for (int it = 0; it < 12; ++it){
    int e = it * 256 + tid; int mm = e / 192; int c = e - mm * 192;
    ys[mm][c] = Ybig[(size_t)(p0 + mm) * 192 + c];
  }
  __syncthreads();
  #pragma unroll
  for (int j = 0; j < 6; ++j){
    int c = t + 16 * j;
    ov[m][c] = wv[c] * ys[m][c] + wv[96 + c] * ys[m][96 + c];
  }
  __syncthreads();
  float res[6];
  #pragma unroll
  for (int j = 0; j < 6; ++j) res[j] = finb[t + 16 * j];
  for (int i = 0; i < 96; ++i){
    float oval = ov[m][i];
    #pragma unroll
    for (int j = 0; j < 6; ++j)
      res[j] = fmaf(finT[i * 96 + t + 16 * j], oval, res[j]);
  }
  #pragma unroll
  for (int j = 0; j < 6; ++j) ys[m][t + 16 * j] = res[j];
  __syncthreads();
  #pragma unroll
  for (int it = 0; it < 6; ++it){
    int e = it * 256 + tid; int c = e >> 4; int mm = e & 15;
    out[((size_t)(b * CHn + c)) * Ll + pp0 + mm] = ys[mm][c];
  }
}

// ---------------- host launch ----------------
extern "C" void kernel_launch(void* const* d_in, const int* in_sizes, int n_in,
                              void* d_out, int out_size, void* d_ws, size_t ws_size,
                              hipStream_t stream) {
  const float* x     = (const float*)d_in[0];
  const float* w1    = (const float*)d_in[1];
  const float* b1    = (const float*)d_in[2];
  const float* bng   = (const float*)d_in[3];
  const float* bnb   = (const float*)d_in[4];
  const float* linw  = (const float*)d_in[5];
  const float* linb  = (const float*)d_in[6];
  const float* dw1w  = (const float*)d_in[7];
  const float* dw1b  = (const float*)d_in[8];
  const float* dw2w  = (const float*)d_in[9];
  const float* dw2b  = (const float*)d_in[10];
  const float* ag1w  = (const float*)d_in[11];
  const float* ag1b  = (const float*)d_in[12];
  const float* ag2w  = (const float*)d_in[13];
  const float* ag2b  = (const float*)d_in[14];
  const float* lng   = (const float*)d_in[15];
  const float* lnb   = (const float*)d_in[16];
  const float* sq1w  = (const float*)d_in[17];
  const float* sq2w  = (const float*)d_in[18];
  const float* gwcw  = (const float*)d_in[19];
  const float* gwcb  = (const float*)d_in[20];
  const float* pwc1w = (const float*)d_in[21];
  const float* pwc2w = (const float*)d_in[22];
  const float* finw  = (const float*)d_in[23];
  const float* finb  = (const float*)d_in[24];
  const float* inw   = (const float*)d_in[25];
  const float* scw   = (const float*)d_in[26];
  const float* scb   = (const float*)d_in[27];
  const float* xpw   = (const float*)d_in[28];
  const float* dtw   = (const float*)d_in[29];
  const float* dtb   = (const float*)d_in[30];
  const float* Alog  = (const float*)d_in[31];
  const float* Dp    = (const float*)d_in[32];
  const float* ong   = (const float*)d_in[33];
  const float* onb   = (const float*)d_in[34];
  const float* oww   = (const float*)d_in[35];

  float* ws = (float*)d_ws;
  float* hlin   = ws + 0;         // 884736
  float* dtsum  = ws + 442368;    // 98304  (scanA->comb)
  float* x1pre  = ws + 884736;    // 884736: x1pre; hinit_lo; csum later
  float* x2     = ws + 1769472;   // 884736: x2; dtsG; hinit_hi
  float* x2g    = ws + 2654208;   // 884736
  float* xibuf  = ws + 3538944;   // 1769472: xi; hend; Ybig
  float* zbuf   = ws + 5308416;   // 1769472
  float* xcbuf  = ws + 7077888;   // 1769472
  float* packed = ws + 8847360;   // 14155776 floats region: part then bf16 packed; ygb/part2 in upper half after scans
  float* bcbuf  = ws + 23003136;  // 1179648
  float* ysum   = ws + 24182784;  // 1769472
  float* wT     = ws + 25952256;  // 142656 weights
  float* xcTbuf = ws + 26094912;  // 1769472

  float* dtsG    = x2;
  float* hend    = xibuf;
  float* hinitlo = x1pre;
  float* hinithi = x2;
  float* ulb     = hlin;
  float* Ybig    = xibuf;
  float* csum_p  = x1pre;
  float* wsmb    = x1pre + 1024;
  float* part    = packed;
  __hip_bfloat16* packedbf = (__hip_bfloat16*)(void*)packed;  // 14155776 bf16 = floats [0, 7077888)
  float* ygb     = packed + 7077888;   // disjoint from bf16 half; used after scans
  float* part2   = packed + 8847360;   // disjoint; used after scans

  float* w1T   = wT + 0;
  float* linT  = wT + 9216;
  float* ag1T  = wT + 18432;
  float* ag2T  = wT + 23040;
  float* inT   = wT + 27648;
  float* owT   = wT + 64512;
  float* pwc1T = wT + 82944;
  float* pwc2T = wT + 85248;
  float* finT  = wT + 86976;
  float* sq1T  = wT + 96192;
  float* sq2T  = wT + 97344;
  float* gwcT  = wT + 98496;
  float* dtwT  = wT + 108864;
  float* xpwT  = wT + 113472;

  TArgs ta;
  const float* srcs[14] = {w1, linw, ag1w, ag2w, inw, oww, pwc1w, pwc2w, finw, sq1w, sq2w, gwcw, dtw, xpw};
  float* dsts[14]       = {w1T, linT, ag1T, ag2T, inT, owT, pwc1T, pwc2T, finT, sq1T, sq2T, gwcT, dtwT, xpwT};
  int rows[14] = {96, 96, 48, 96, 384, 96, 96, 72, 96, 24, 24, 96, 768, 152};
  int cols[14] = {96, 96, 96, 48, 96, 192, 24, 24, 96, 48, 48, 108, 6, 192};
  for (int i = 0; i < 14; ++i){ ta.s[i] = srcs[i]; ta.d[i] = dsts[i]; ta.rows[i] = rows[i]; ta.cols[i] = cols[i]; }

  k_tr<<<dim3(144, 14), 256, 0, stream>>>(ta);
  k_pre<<<576, 256, 0, stream>>>(x, w1T, b1, bng, bnb, linT, linb, hlin);
  k_dw<<<(Pp * CHn) / 256, 256, 0, stream>>>(hlin, dw1w, dw1b, dw2w, dw2b, x1pre, x2);
  k_gate<<<576, 256, 0, stream>>>(x2, ag1T, ag1b, ag2T, ag2b, x2g);
  k_ssin<<<576 * 3, 256, 0, stream>>>(x1pre, inT, xibuf, zbuf);
  k_ssdw<<<(Pp * DIn) / 256, 256, 0, stream>>>(xibuf, scw, scb, xcbuf, xcTbuf);
  k_xproj<<<288 * 6, 256, 0, stream>>>(xcbuf, xpwT, part);
  k_xred<<<(Pp * 152 + 255) / 256, 256, 0, stream>>>(part, bcbuf, dtsG);
  k_pack<<<(36864 * DIn) / 256, 256, 0, stream>>>(dtsG, dtwT, dtb, xcbuf, xcTbuf, packedbf);
  k_scanA<<<192 * Sseg, 64, 0, stream>>>(packedbf, bcbuf, Alog, hend, dtsum);
  k_comb<<<192, 64, 0, stream>>>(Alog, hend, dtsum, hinitlo, hinithi, ysum);
  k_scanB<<<192 * Sseg, 64, 0, stream>>>(packedbf, bcbuf, Alog, hinitlo, hinithi, ysum);
  k_lngate<<<2304, 256, 0, stream>>>(ysum, xcbuf, zbuf, Dp, ong, onb, ygb);
  k_oproj<<<1152, 256, 0, stream>>>(ygb, owT, part2);
  k_finc<<<576, 256, 0, stream>>>(part2, x2g, lng, lnb, sq1T, sq2T, ulb, csum_p);
  k_y<<<576, 256, 0, stream>>>(ulb, gwcT, gwcb, pwc1T, pwc2T, Ybig, csum_p);
  k_softmax<<<4, 192, 0, stream>>>(csum_p, wsmb);
  k_final<<<576, 256, 0, stream>>>(Ybig, wsmb, finT, finb, (float*)d_out);
}